// Round 3
// baseline (1017.894 us; speedup 1.0000x reference)
//
#include <hip/hip_runtime.h>
#include <math.h>

#define N_TOK  131072
#define DIM    1024
#define HIDN   256
#define ATTN   128
#define NSEG   64
#define SEGLEN 2048
#define EPSLN  1e-5f

typedef __attribute__((ext_vector_type(8))) short  short8;
typedef __attribute__((ext_vector_type(4))) float  f32x4;

__device__ __forceinline__ unsigned short f2bf(float f) {
    unsigned int u = __float_as_uint(f);
    u += 0x7fffu + ((u >> 16) & 1u);
    return (unsigned short)(u >> 16);
}
__device__ __forceinline__ float bf2f(unsigned short h) {
    return __uint_as_float(((unsigned int)h) << 16);
}
__device__ __forceinline__ float gelu_exact(float x) {
    return 0.5f * x * (1.0f + erff(x * 0.70710678118654752f));
}

// out[C][R] (bf16) = transpose(in[R][C] fp32)
__global__ __launch_bounds__(256) void transpose_cvt(const float* __restrict__ in,
                                                     unsigned short* __restrict__ out,
                                                     int R, int C) {
    __shared__ float t[32][33];
    const int bx = blockIdx.x * 32, by = blockIdx.y * 32;
    const int x = threadIdx.x, y = threadIdx.y;  // 32 x 8
#pragma unroll
    for (int i = 0; i < 32; i += 8) {
        int r = by + y + i, c = bx + x;
        if (r < R && c < C) t[y + i][x] = in[(size_t)r * C + c];
    }
    __syncthreads();
#pragma unroll
    for (int i = 0; i < 32; i += 8) {
        int c = bx + y + i, r = by + x;
        if (c < C && r < R) out[(size_t)c * R + r] = f2bf(t[x][y + i]);
    }
}

// Interleaved attention weight: Wt[c][k] = bf16( (c&1) ? Wu[k][c>>1] : Wv[k][c>>1] ),
// so (v,u) for one attention unit live in adjacent MFMA output lanes.
__global__ __launch_bounds__(256) void build_vu(const float* __restrict__ Wv,
                                                const float* __restrict__ Wu,
                                                const float* __restrict__ bv,
                                                const float* __restrict__ bu,
                                                unsigned short* __restrict__ Wt,
                                                float* __restrict__ bvu) {
    const int c = blockIdx.x, k = threadIdx.x;     // 256 x 256
    const float* src = (c & 1) ? Wu : Wv;
    Wt[(size_t)c * HIDN + k] = f2bf(src[(size_t)k * ATTN + (c >> 1)]);
    if (k == 0) bvu[c] = (c & 1) ? bu[c >> 1] : bv[c >> 1];
}

// Shared main loop: 64x256 tile, BK=32, 256 thr / 4 waves; wave w owns cols [64w,64w+64).
// As/Ws rows padded to 40 shorts (80 B) for bank spread.
template <int K, bool AF32>
__device__ __forceinline__ void gemm_mainloop(const void* __restrict__ Aptr,
                                              const unsigned short* __restrict__ Wt,
                                              unsigned short (*As)[40],
                                              unsigned short (*Ws)[40],
                                              f32x4 acc[4][4],
                                              int tid, size_t row0) {
    const int wave = tid >> 6, lane = tid & 63;
    const int lr = lane & 15, lq = lane >> 4;
    const int srow = tid >> 2, skq = (tid & 3) * 8;

#pragma unroll
    for (int i = 0; i < 4; i++)
#pragma unroll
        for (int j = 0; j < 4; j++) acc[i][j] = (f32x4)0.0f;

    for (int k0 = 0; k0 < K; k0 += 32) {
        short8 aw;
        if constexpr (AF32) {
            const float* A = (const float*)Aptr;
            const float* p = &A[(row0 + srow) * K + k0 + skq];
            float4 v0 = *(const float4*)p;
            float4 v1 = *(const float4*)(p + 4);
            aw[0] = (short)f2bf(v0.x); aw[1] = (short)f2bf(v0.y);
            aw[2] = (short)f2bf(v0.z); aw[3] = (short)f2bf(v0.w);
            aw[4] = (short)f2bf(v1.x); aw[5] = (short)f2bf(v1.y);
            aw[6] = (short)f2bf(v1.z); aw[7] = (short)f2bf(v1.w);
        } else {
            const unsigned short* A = (const unsigned short*)Aptr;
            aw = *(const short8*)&A[(row0 + srow) * K + k0 + skq];
        }
        short8 ww[4];
#pragma unroll
        for (int c = 0; c < 4; c++)
            ww[c] = *(const short8*)&Wt[(size_t)(srow + 64 * c) * K + k0 + skq];

        __syncthreads();
        *(short8*)&As[srow][skq] = aw;
#pragma unroll
        for (int c = 0; c < 4; c++)
            *(short8*)&Ws[srow + 64 * c][skq] = ww[c];
        __syncthreads();

        short8 a[4], b[4];
#pragma unroll
        for (int i = 0; i < 4; i++) a[i] = *(const short8*)&As[16 * i + lr][lq * 8];
#pragma unroll
        for (int j = 0; j < 4; j++) b[j] = *(const short8*)&Ws[64 * wave + 16 * j + lr][lq * 8];
#pragma unroll
        for (int i = 0; i < 4; i++)
#pragma unroll
            for (int j = 0; j < 4; j++)
                acc[i][j] = __builtin_amdgcn_mfma_f32_16x16x32_bf16(a[i], b[j], acc[i][j], 0, 0, 0);
    }
}

// GEMM + bias + LayerNorm + GELU -> bf16 out. One block = 64 complete rows.
template <int K, bool AF32>
__global__ __launch_bounds__(256) void gemm_ln_gelu(const void* __restrict__ Aptr,
                                                    const unsigned short* __restrict__ Wt,
                                                    const float* __restrict__ bias,
                                                    const float* __restrict__ g,
                                                    const float* __restrict__ be,
                                                    unsigned short* __restrict__ Hout) {
    __shared__ __align__(16) char smem[36352];
    unsigned short (*As)[40] = (unsigned short(*)[40])smem;
    unsigned short (*Ws)[40] = (unsigned short(*)[40])(smem + 5120);
    const int tid = threadIdx.x;
    const size_t row0 = (size_t)blockIdx.x * 64;

    f32x4 acc[4][4];
    gemm_mainloop<K, AF32>(Aptr, Wt, As, Ws, acc, tid, row0);

    const int wave = tid >> 6, lane = tid & 63;
    const int lr = lane & 15, lq = lane >> 4;

    // bias
    float bj[4];
#pragma unroll
    for (int j = 0; j < 4; j++) bj[j] = bias[wave * 64 + 16 * j + lr];
#pragma unroll
    for (int i = 0; i < 4; i++)
#pragma unroll
        for (int j = 0; j < 4; j++)
#pragma unroll
            for (int r = 0; r < 4; r++) acc[i][j][r] += bj[j];

    float* sums  = (float*)(smem + 33792);   // [64][4]
    float* sumsq = (float*)(smem + 34816);   // [64][4]
    float* muA   = (float*)(smem + 35840);   // [64]
    float* rinvA = (float*)(smem + 36096);   // [64]

    __syncthreads();   // staging LDS dead; safe to reuse smem regions
#pragma unroll
    for (int i = 0; i < 4; i++)
#pragma unroll
        for (int r = 0; r < 4; r++) {
            float s = 0.0f, q = 0.0f;
#pragma unroll
            for (int j = 0; j < 4; j++) {
                float v = acc[i][j][r];
                s += v; q += v * v;
            }
#pragma unroll
            for (int o = 1; o < 16; o <<= 1) {
                s += __shfl_xor(s, o);
                q += __shfl_xor(q, o);
            }
            if (lr == 0) {
                int row = 16 * i + lq * 4 + r;
                sums[row * 4 + wave]  = s;
                sumsq[row * 4 + wave] = q;
            }
        }
    __syncthreads();
    if (tid < 64) {
        float S = sums[tid * 4] + sums[tid * 4 + 1] + sums[tid * 4 + 2] + sums[tid * 4 + 3];
        float Q = sumsq[tid * 4] + sumsq[tid * 4 + 1] + sumsq[tid * 4 + 2] + sumsq[tid * 4 + 3];
        float m_ = S * (1.0f / HIDN);
        float v_ = Q * (1.0f / HIDN) - m_ * m_;
        muA[tid]   = m_;
        rinvA[tid] = rsqrtf(v_ + EPSLN);
    }
    __syncthreads();

    unsigned short* outb = (unsigned short*)smem;   // [64][264]
    float gj[4], bej[4];
#pragma unroll
    for (int j = 0; j < 4; j++) {
        int col = wave * 64 + 16 * j + lr;
        gj[j] = g[col]; bej[j] = be[col];
    }
#pragma unroll
    for (int i = 0; i < 4; i++)
#pragma unroll
        for (int r = 0; r < 4; r++) {
            int row = 16 * i + lq * 4 + r;
            float m_ = muA[row], rv = rinvA[row];
#pragma unroll
            for (int j = 0; j < 4; j++) {
                float val = (acc[i][j][r] - m_) * rv * gj[j] + bej[j];
                outb[row * 264 + wave * 64 + 16 * j + lr] = f2bf(gelu_exact(val));
            }
        }
    __syncthreads();
#pragma unroll
    for (int m = 0; m < 8; m++) {
        int u = tid + 256 * m;            // 2048 ushort8 units
        int row = u >> 5, cb = u & 31;
        short8 v = *(const short8*)&outb[row * 264 + cb * 8];
        *(short8*)&Hout[(row0 + row) * 256 + cb * 8] = v;
    }
}

// GEMM(VU, interleaved) + tanh*sigmoid*Ww row-reduce -> scores. Writes 64 floats/block.
template <int K>
__global__ __launch_bounds__(256) void gemm_score(const unsigned short* __restrict__ Aptr,
                                                  const unsigned short* __restrict__ Wt,
                                                  const float* __restrict__ bvu,
                                                  const float* __restrict__ Ww,
                                                  const float* __restrict__ bw,
                                                  float* __restrict__ Aout) {
    __shared__ __align__(16) char smem[26624];
    unsigned short (*As)[40] = (unsigned short(*)[40])smem;
    unsigned short (*Ws)[40] = (unsigned short(*)[40])(smem + 5120);
    float* ssum = (float*)(smem + 25600);   // [64][4]
    const int tid = threadIdx.x;
    const size_t row0 = (size_t)blockIdx.x * 64;

    f32x4 acc[4][4];
    gemm_mainloop<K, false>(Aptr, Wt, As, Ws, acc, tid, row0);

    const int wave = tid >> 6, lane = tid & 63;
    const int lr = lane & 15, lq = lane >> 4;

    float bj[4], wwj[4];
#pragma unroll
    for (int j = 0; j < 4; j++) {
        bj[j]  = bvu[wave * 64 + 16 * j + lr];
        wwj[j] = Ww[wave * 32 + 8 * j + (lr >> 1)];
    }
    const float bw0 = bw[0];

    __syncthreads();
#pragma unroll
    for (int i = 0; i < 4; i++)
#pragma unroll
        for (int r = 0; r < 4; r++) {
            float s = 0.0f;
#pragma unroll
            for (int j = 0; j < 4; j++) {
                float v = acc[i][j][r] + bj[j];
                float p = __shfl_xor(v, 1);   // partner: u for even lanes
                float c = tanhf(v) * (1.0f / (1.0f + expf(-p))) * wwj[j];
                s += ((lr & 1) == 0) ? c : 0.0f;
            }
#pragma unroll
            for (int o = 1; o < 16; o <<= 1) s += __shfl_xor(s, o);
            if (lr == 0) ssum[(16 * i + lq * 4 + r) * 4 + wave] = s;
        }
    __syncthreads();
    if (tid < 64)
        Aout[row0 + tid] = ssum[tid * 4] + ssum[tid * 4 + 1] + ssum[tid * 4 + 2] + ssum[tid * 4 + 3] + bw0;
}

// In-place softmax over each contiguous segment of 2048 scores.
__global__ __launch_bounds__(256) void seg_softmax(float* __restrict__ A) {
    __shared__ float red[256];
    const int seg = blockIdx.x, tid = threadIdx.x;
    float* a = A + (size_t)seg * SEGLEN;
    float m = -1e30f;
#pragma unroll
    for (int c = 0; c < 8; c++) m = fmaxf(m, a[tid + 256 * c]);
    red[tid] = m; __syncthreads();
    for (int s = 128; s > 0; s >>= 1) {
        if (tid < s) red[tid] = fmaxf(red[tid], red[tid + s]);
        __syncthreads();
    }
    m = red[0]; __syncthreads();
    float e[8]; float sum = 0.0f;
#pragma unroll
    for (int c = 0; c < 8; c++) { e[c] = expf(a[tid + 256 * c] - m); sum += e[c]; }
    red[tid] = sum; __syncthreads();
    for (int s = 128; s > 0; s >>= 1) {
        if (tid < s) red[tid] += red[tid + s];
        __syncthreads();
    }
    const float inv = 1.0f / red[0];
#pragma unroll
    for (int c = 0; c < 8; c++) a[tid + 256 * c] = e[c] * inv;
}

// Zp[b][col] = sum over 256 rows (b = seg*8+chunk) of attn[row]*h[row][col]
__global__ __launch_bounds__(256) void pool_partial(const float* __restrict__ Attn,
                                                    const unsigned short* __restrict__ H,
                                                    float* __restrict__ Zp) {
    __shared__ float aw[256];
    const int tid = threadIdx.x;
    const size_t rbase = (size_t)blockIdx.x * 256;
    aw[tid] = Attn[rbase + tid];
    __syncthreads();
    const unsigned short* h = H + rbase * 256 + tid;
    float acc = 0.0f;
    for (int r = 0; r < 256; r++) acc += aw[r] * bf2f(h[(size_t)r * 256]);
    Zp[rbase + tid] = acc;
}

// z = sum of 8 partials; logits = gelu(z @ Wc1 + bc1) @ Wc2 + bc2.
__global__ __launch_bounds__(256) void head_kernel(const float* __restrict__ Zp,
                                                   const float* __restrict__ Wc1,
                                                   const float* __restrict__ bc1,
                                                   const float* __restrict__ Wc2,
                                                   const float* __restrict__ bc2,
                                                   float* __restrict__ Out) {
    __shared__ float zs[256];
    __shared__ float hs[128];
    __shared__ float red[4];
    const int seg = blockIdx.x, tid = threadIdx.x;
    float z = 0.0f;
#pragma unroll
    for (int c = 0; c < 8; c++) z += Zp[((size_t)seg * 8 + c) * 256 + tid];
    zs[tid] = z;
    __syncthreads();
    if (tid < 128) {
        float acc = bc1[tid];
        for (int k = 0; k < 256; k++) acc += zs[k] * Wc1[k * 128 + tid];
        hs[tid] = gelu_exact(acc);
    }
    __syncthreads();
    const int cls = tid >> 7, j = tid & 127;
    float val = hs[j] * Wc2[j * 2 + cls];
#pragma unroll
    for (int o = 32; o > 0; o >>= 1) val += __shfl_down(val, o);
    if ((tid & 63) == 0) red[tid >> 6] = val;
    __syncthreads();
    if (tid < 2) Out[seg * 2 + tid] = red[tid * 2] + red[tid * 2 + 1] + bc2[tid];
}

extern "C" void kernel_launch(void* const* d_in, const int* in_sizes, int n_in,
                              void* d_out, int out_size, void* d_ws, size_t ws_size,
                              hipStream_t stream) {
    const float* x   = (const float*)d_in[0];
    const float* W1  = (const float*)d_in[2];
    const float* b1  = (const float*)d_in[3];
    const float* g1  = (const float*)d_in[4];
    const float* be1 = (const float*)d_in[5];
    const float* W2  = (const float*)d_in[6];
    const float* b2  = (const float*)d_in[7];
    const float* g2  = (const float*)d_in[8];
    const float* be2 = (const float*)d_in[9];
    const float* Wv  = (const float*)d_in[10];
    const float* bv  = (const float*)d_in[11];
    const float* Wu  = (const float*)d_in[12];
    const float* bu  = (const float*)d_in[13];
    const float* Ww  = (const float*)d_in[14];
    const float* bw  = (const float*)d_in[15];
    const float* Wc1 = (const float*)d_in[16];
    const float* bc1 = (const float*)d_in[17];
    const float* Wc2 = (const float*)d_in[18];
    const float* bc2 = (const float*)d_in[19];
    float* out = (float*)d_out;

    char* p = (char*)d_ws;
    unsigned short* h1b    = (unsigned short*)p; p += (size_t)N_TOK * HIDN * 2;  // 67 MB
    unsigned short* h2b    = (unsigned short*)p; p += (size_t)N_TOK * HIDN * 2;  // 67 MB
    float*          scores = (float*)p;          p += (size_t)N_TOK * 4;
    unsigned short* W1t    = (unsigned short*)p; p += (size_t)HIDN * DIM * 2;
    unsigned short* W2t    = (unsigned short*)p; p += (size_t)HIDN * HIDN * 2;
    unsigned short* Wvut   = (unsigned short*)p; p += (size_t)HIDN * HIDN * 2;
    float*          bvu    = (float*)p;          p += 256 * 4;
    float*          Zp     = (float*)p;          p += (size_t)NSEG * 8 * HIDN * 4;

    dim3 tb(32, 8);
    transpose_cvt<<<dim3(HIDN / 32, DIM / 32), tb, 0, stream>>>(W1, W1t, DIM, HIDN);
    transpose_cvt<<<dim3(HIDN / 32, HIDN / 32), tb, 0, stream>>>(W2, W2t, HIDN, HIDN);
    build_vu<<<256, 256, 0, stream>>>(Wv, Wu, bv, bu, Wvut, bvu);

    gemm_ln_gelu<DIM, true><<<N_TOK / 64, 256, 0, stream>>>(x, W1t, b1, g1, be1, h1b);
    gemm_ln_gelu<HIDN, false><<<N_TOK / 64, 256, 0, stream>>>(h1b, W2t, b2, g2, be2, h2b);
    gemm_score<HIDN><<<N_TOK / 64, 256, 0, stream>>>(h2b, Wvut, bvu, Ww, bw, scores);
    seg_softmax<<<NSEG, 256, 0, stream>>>(scores);
    pool_partial<<<NSEG * 8, 256, 0, stream>>>(scores, h2b, Zp);
    head_kernel<<<NSEG, 256, 0, stream>>>(Zp, Wc1, bc1, Wc2, bc2, out);
}